// Round 12
// baseline (249.947 us; speedup 1.0000x reference)
//
#include <hip/hip_runtime.h>
#include <type_traits>

// GraphSAGE 2-layer, N=100k, C 128->128->64, E=1.6M, fp32 in/out.
// R9/R10: latency-optimized quarter-per-node aggregation.
// R11-R15: fused-panel persistent GEMM.
// R16: cooperative mega-kernel FAILED (coop launch vs graph capture).
// R17: wprep deleted (direct fp32-B load) — VALIDATED.
// R18: bfill+agg128 fusion REGRESSED (tiny grid). Reverted.
// R19: single-pass slotted scatter (bhist+bscatter merged) — 245.7us BEST.
// R20: scatter occupancy fix (EB 4096->2048: 1.5 -> 3 blocks/CU for the
//      latency-bound scattered writes) + btop deleted (bfill computes its
//      own bucket prefix via masked reduce). 7 dispatches.

constexpr int K = 128;
constexpr int EB = 2048;     // edges per partition block (R20: halved)
constexpr int CAP = 8192;    // slots per bucket (mean 4092, +64 sigma)

typedef __bf16 bf16x2 __attribute__((ext_vector_type(2)));
typedef __bf16 bf16x4 __attribute__((ext_vector_type(4)));
typedef __bf16 bf16x8 __attribute__((ext_vector_type(8)));
typedef float f32x4 __attribute__((ext_vector_type(4)));
typedef float f32x2 __attribute__((ext_vector_type(2)));

// ---------------- fp8 e4m3 conversion ----------------

__device__ __forceinline__ unsigned char to_fp8(float v) {
#if __has_builtin(__builtin_amdgcn_cvt_pk_fp8_f32)
  int p = __builtin_amdgcn_cvt_pk_fp8_f32(v, v, 0, false);
  return (unsigned char)(p & 0xff);
#else
  unsigned u = __builtin_bit_cast(unsigned, v);
  unsigned s = (u >> 24) & 0x80u;
  float a = fabsf(v);
  if (a > 448.f) a = 448.f;
  unsigned bits;
  if (a < 0.015625f) {
    bits = (unsigned)(a * 512.f + 0.5f);
  } else {
    unsigned b = __builtin_bit_cast(unsigned, a);
    b += ((b >> 20) & 1) + 0x0007FFFF;
    unsigned e = (b >> 23) - 120;
    bits = (e << 3) | ((b >> 20) & 7);
    if (bits > 0x7E) bits = 0x7E;
  }
  return (unsigned char)(s | bits);
#endif
}

__device__ __forceinline__ f32x2 from_fp8x2(unsigned short u) {
#if __has_builtin(__builtin_amdgcn_cvt_pk_f32_fp8)
  return __builtin_amdgcn_cvt_pk_f32_fp8((int)u, false);
#else
  f32x2 r;
  unsigned b0 = u & 0xff, b1 = (u >> 8) & 0xff;
  unsigned e0 = (b0 >> 3) & 15, m0 = b0 & 7;
  unsigned e1 = (b1 >> 3) & 15, m1 = b1 & 7;
  float v0 = e0 ? __builtin_bit_cast(float, ((e0 + 120) << 23) | (m0 << 20))
              : (float)m0 * 0.001953125f;
  float v1 = e1 ? __builtin_bit_cast(float, ((e1 + 120) << 23) | (m1 << 20))
              : (float)m1 * 0.001953125f;
  r[0] = (b0 & 0x80) ? -v0 : v0;
  r[1] = (b1 & 0x80) ? -v1 : v1;
  return r;
#endif
}

__device__ __forceinline__ f32x2 fp8x2_lo(unsigned v) {
#if __has_builtin(__builtin_amdgcn_cvt_pk_f32_fp8)
  return __builtin_amdgcn_cvt_pk_f32_fp8((int)v, false);
#else
  return from_fp8x2((unsigned short)(v & 0xffffu));
#endif
}

__device__ __forceinline__ f32x2 fp8x2_hi(unsigned v) {
#if __has_builtin(__builtin_amdgcn_cvt_pk_f32_fp8)
  return __builtin_amdgcn_cvt_pk_f32_fp8((int)v, true);
#else
  return from_fp8x2((unsigned short)(v >> 16));
#endif
}

// ---------------- single-pass bucketed scatter (slotted layout) ----------------
// Per block: LDS hist of its edge range -> reserve a contiguous range in
// each touched bucket via ONE global atomicAdd -> LDS-cursor scatter into
// recs[bucket*CAP + slot].

__global__ __launch_bounds__(256) void k_scatter(const int* __restrict__ src,
                                                 const int* __restrict__ dst,
                                                 int* __restrict__ bucketCount,
                                                 unsigned* __restrict__ recs,
                                                 int E, int n, int nB) {
  extern __shared__ int cur[];
  for (int i = threadIdx.x; i < nB; i += 256) cur[i] = 0;
  __syncthreads();
  int base = blockIdx.x * EB, end = min(base + EB, E);
  for (int e = base + threadIdx.x; e < end; e += 256) {
    int d = dst[e];
    if ((unsigned)d < (unsigned)n) atomicAdd(&cur[d >> 8], 1);
  }
  __syncthreads();
  for (int i = threadIdx.x; i < nB; i += 256) {
    int c = cur[i];
    cur[i] = c ? atomicAdd(&bucketCount[i], c) : 0;
  }
  __syncthreads();
  for (int e = base + threadIdx.x; e < end; e += 256) {
    int d = dst[e];
    if ((unsigned)d < (unsigned)n) {
      int s = min(max(src[e], 0), n - 1);
      int b = d >> 8;
      int pos = min(atomicAdd(&cur[b], 1), CAP - 1);  // clamp: OOB-safe
      recs[(long)b * CAP + pos] = ((unsigned)s << 8) | (unsigned)(d & 255);
    }
  }
}

// Per-bucket rowptr + col fill from the slotted recs region. R20: computes
// its own bucket prefix (masked reduce over bucketCount) — btop deleted.
__global__ __launch_bounds__(256) void k_bfill(const unsigned* __restrict__ recs,
                                               const int* __restrict__ bucketCount,
                                               int* __restrict__ rowptr,
                                               int* __restrict__ col, int n) {
  __shared__ int degl[256];
  __shared__ int incl[256];
  __shared__ int red[256];
  int b = blockIdx.x, t = threadIdx.x;

  // prefix: rbeg = sum(bucketCount[0..b)) — L2-hot, ~2 loads/thread
  int partial = 0;
  for (int i = t; i < b; i += 256) partial += bucketCount[i];
  red[t] = partial;
  __syncthreads();
  for (int off = 128; off > 0; off >>= 1) {
    if (t < off) red[t] += red[t + off];
    __syncthreads();
  }
  int rbeg = red[0];
  int cnt = bucketCount[b];
  const unsigned* rbase = recs + (long)b * CAP;
  __syncthreads();

  degl[t] = 0;
  __syncthreads();
  for (int i = t; i < cnt; i += 256)
    atomicAdd(&degl[rbase[i] & 255], 1);
  __syncthreads();
  incl[t] = degl[t];
  __syncthreads();
  for (int off = 1; off < 256; off <<= 1) {
    int v = (t >= off) ? incl[t - off] : 0;
    __syncthreads();
    incl[t] += v;
    __syncthreads();
  }
  int excl = incl[t] - degl[t];
  int node = b * 256 + t;
  if (node <= n) rowptr[node] = rbeg + excl;
  __syncthreads();
  degl[t] = rbeg + excl;  // reuse as cursor
  __syncthreads();
  for (int i = t; i < cnt; i += 256) {
    unsigned r = rbase[i];
    int pos = atomicAdd(&degl[r & 255], 1);
    col[pos] = (int)(r >> 8);
  }
}

// ---------------- persistent fused-panel GEMM (direct fp32 B) ----------------
// Block = 64-row tiles (grid-stride), 512 threads (8 waves). Wave w:
// panel = w>>2 (Wl->fp8 / Wr->bf16), col strip (w&3)*16*NI, NI=COLS/64.
// B fragments: in-register transposing load from fp32 W + bf16 cast,
// pinned once per block. Double-buffered LDS A with register prefetch.

template <int COLS, typename TIN>
__global__ __launch_bounds__(512, 4) void k_gemm_fused(const TIN* __restrict__ X,
                                                       const float* __restrict__ Wa,
                                                       const float* __restrict__ Wb,
                                                       unsigned char* __restrict__ outA,
                                                       __bf16* __restrict__ outB,
                                                       int nrows, int ntiles) {
  constexpr int LD = 136;
  constexpr int NI = COLS / 64;
  constexpr bool FP32IN = std::is_same_v<TIN, float>;
  __shared__ __bf16 As[2][64 * LD];

  int tid = threadIdx.x;
  int w = tid >> 6, lane = tid & 63;
  int m = lane & 15, quad = lane >> 4;
  int panel = w >> 2;
  int wcol = (w & 3) * (16 * NI);
  const float* Wsrc = panel ? Wb : Wa;

  bf16x8 bq[4][NI];
#pragma unroll
  for (int kc = 0; kc < 4; ++kc)
#pragma unroll
    for (int ni = 0; ni < NI; ++ni)
#pragma unroll
      for (int e = 0; e < 8; ++e)
        bq[kc][ni][e] = (__bf16)Wsrc[(kc * 32 + quad * 8 + e) * COLS + (wcol + ni * 16 + m)];

  float4 ra[4];
  bf16x8 rb[2];

  auto load_tile = [&](int t) {
    long row0 = (long)t * 64;
    if constexpr (FP32IN) {
#pragma unroll
      for (int it = 0; it < 4; ++it) {
        int i = tid + it * 512;
        int r = i >> 5, c4 = (i & 31) << 2;
        long row = row0 + r;
        float4 v = make_float4(0.f, 0.f, 0.f, 0.f);
        if (row < nrows) v = *(const float4*)(X + row * K + c4);
        ra[it] = v;
      }
    } else {
#pragma unroll
      for (int it = 0; it < 2; ++it) {
        int i = tid + it * 512;
        int r = i >> 4, c8 = (i & 15) << 3;
        long row = row0 + r;
        bf16x8 v = {};
        if (row < nrows) v = *(const bf16x8*)(X + row * K + c8);
        rb[it] = v;
      }
    }
  };

  auto write_tile = [&](int buf) {
    if constexpr (FP32IN) {
#pragma unroll
      for (int it = 0; it < 4; ++it) {
        int i = tid + it * 512;
        int r = i >> 5, c4 = (i & 31) << 2;
        bf16x4 bb;
        bb[0] = (__bf16)ra[it].x; bb[1] = (__bf16)ra[it].y;
        bb[2] = (__bf16)ra[it].z; bb[3] = (__bf16)ra[it].w;
        *(bf16x4*)&As[buf][r * LD + c4] = bb;
      }
    } else {
#pragma unroll
      for (int it = 0; it < 2; ++it) {
        int i = tid + it * 512;
        int r = i >> 4, c8 = (i & 15) << 3;
        *(bf16x8*)&As[buf][r * LD + c8] = rb[it];
      }
    }
  };

  int t = (int)blockIdx.x;
  int stride = (int)gridDim.x;
  if (t < ntiles) load_tile(t);

#pragma unroll
  for (int kc = 0; kc < 4; ++kc)
#pragma unroll
    for (int ni = 0; ni < NI; ++ni)
      asm volatile("" :: "v"(bq[kc][ni]));

  int buf = 0;
  while (t < ntiles) {
    write_tile(buf);
    __syncthreads();
    int tn = t + stride;
    if (tn < ntiles) load_tile(tn);  // prefetch under compute

    f32x4 acc[4][NI];
#pragma unroll
    for (int mi = 0; mi < 4; ++mi)
#pragma unroll
      for (int ni = 0; ni < NI; ++ni) acc[mi][ni] = (f32x4){0.f, 0.f, 0.f, 0.f};

#pragma unroll
    for (int kc = 0; kc < 4; ++kc) {
      int ko = kc * 32 + quad * 8;
      bf16x8 af[4];
#pragma unroll
      for (int mi = 0; mi < 4; ++mi)
        af[mi] = *(const bf16x8*)&As[buf][(mi * 16 + m) * LD + ko];
#pragma unroll
      for (int mi = 0; mi < 4; ++mi)
#pragma unroll
        for (int ni = 0; ni < NI; ++ni)
          acc[mi][ni] = __builtin_amdgcn_mfma_f32_16x16x32_bf16(af[mi], bq[kc][ni], acc[mi][ni], 0, 0, 0);
    }

    long row0 = (long)t * 64;
#pragma unroll
    for (int mi = 0; mi < 4; ++mi) {
#pragma unroll
      for (int r = 0; r < 4; ++r) {
        long grow = row0 + mi * 16 + quad * 4 + r;
        if (grow < nrows) {
#pragma unroll
          for (int ni = 0; ni < NI; ++ni) {
            long idx = grow * COLS + wcol + ni * 16 + m;
            float v = acc[mi][ni][r];
            if (panel == 0) outA[idx] = to_fp8(v);
            else            outB[idx] = (__bf16)v;
          }
        }
      }
    }
    t = tn;
    buf ^= 1;
  }
}

// ---------------- aggregation (proven R10 structure, full grids) ----------------

template <bool RELU>
__global__ __launch_bounds__(256) void k_agg128(const unsigned char* __restrict__ Y,
                                                const __bf16* __restrict__ XR,
                                                const float* __restrict__ bias,
                                                const int* __restrict__ rowptr,
                                                const int* __restrict__ col,
                                                __bf16* __restrict__ out, int nnodes) {
  int wave = threadIdx.x >> 6, lane = threadIdx.x & 63;
  int quarter = lane >> 4, l = lane & 15;
  int sb = lane & 48;
  int n = blockIdx.x * 16 + wave * 4 + quarter;
  bool valid = n < nnodes;
  int beg = 0, end = 0;
  if (valid) {
    beg = rowptr[n];
    end = rowptr[n + 1];
  }
  int co = l * 8;
  const unsigned char* Yc = Y + co;

  f32x2 av0 = {0.f, 0.f}, av1 = {0.f, 0.f}, av2 = {0.f, 0.f}, av3 = {0.f, 0.f};

  for (int base = beg; base < end; base += 16) {
    int cnt = min(end - base, 16);
    int idx = (l < cnt) ? col[base + l] : 0;
    int j = 0;
    for (; j + 3 < cnt; j += 4) {
      long s0 = (unsigned)__shfl(idx, sb + j);
      long s1 = (unsigned)__shfl(idx, sb + j + 1);
      long s2 = (unsigned)__shfl(idx, sb + j + 2);
      long s3 = (unsigned)__shfl(idx, sb + j + 3);
      uint2 v0 = *(const uint2*)(Yc + s0 * 128);
      uint2 v1 = *(const uint2*)(Yc + s1 * 128);
      uint2 v2 = *(const uint2*)(Yc + s2 * 128);
      uint2 v3 = *(const uint2*)(Yc + s3 * 128);
      av0 += fp8x2_lo(v0.x); av1 += fp8x2_hi(v0.x);
      av2 += fp8x2_lo(v0.y); av3 += fp8x2_hi(v0.y);
      av0 += fp8x2_lo(v1.x); av1 += fp8x2_hi(v1.x);
      av2 += fp8x2_lo(v1.y); av3 += fp8x2_hi(v1.y);
      av0 += fp8x2_lo(v2.x); av1 += fp8x2_hi(v2.x);
      av2 += fp8x2_lo(v2.y); av3 += fp8x2_hi(v2.y);
      av0 += fp8x2_lo(v3.x); av1 += fp8x2_hi(v3.x);
      av2 += fp8x2_lo(v3.y); av3 += fp8x2_hi(v3.y);
    }
    for (; j < cnt; ++j) {
      long s = (unsigned)__shfl(idx, sb + j);
      uint2 v = *(const uint2*)(Yc + s * 128);
      av0 += fp8x2_lo(v.x); av1 += fp8x2_hi(v.x);
      av2 += fp8x2_lo(v.y); av3 += fp8x2_hi(v.y);
    }
  }

  if (valid) {
    float inv = 1.f / (float)max(end - beg, 1);
    bf16x8 xv = *(const bf16x8*)(XR + (long)n * 128 + co);
    f32x4 b0 = *(const f32x4*)(bias + co);
    f32x4 b1 = *(const f32x4*)(bias + co + 4);
    float r0 = av0[0] * inv + (float)xv[0] + b0[0];
    float r1 = av0[1] * inv + (float)xv[1] + b0[1];
    float r2 = av1[0] * inv + (float)xv[2] + b0[2];
    float r3 = av1[1] * inv + (float)xv[3] + b0[3];
    float r4 = av2[0] * inv + (float)xv[4] + b1[0];
    float r5 = av2[1] * inv + (float)xv[5] + b1[1];
    float r6 = av3[0] * inv + (float)xv[6] + b1[2];
    float r7 = av3[1] * inv + (float)xv[7] + b1[3];
    if (RELU) {
      r0 = fmaxf(r0, 0.f); r1 = fmaxf(r1, 0.f);
      r2 = fmaxf(r2, 0.f); r3 = fmaxf(r3, 0.f);
      r4 = fmaxf(r4, 0.f); r5 = fmaxf(r5, 0.f);
      r6 = fmaxf(r6, 0.f); r7 = fmaxf(r7, 0.f);
    }
    bf16x8 o;
    o[0] = (__bf16)r0; o[1] = (__bf16)r1; o[2] = (__bf16)r2; o[3] = (__bf16)r3;
    o[4] = (__bf16)r4; o[5] = (__bf16)r5; o[6] = (__bf16)r6; o[7] = (__bf16)r7;
    *(bf16x8*)(out + (long)n * 128 + co) = o;
  }
}

__global__ __launch_bounds__(256) void k_agg64(const unsigned char* __restrict__ Y,
                                               const __bf16* __restrict__ XR,
                                               const float* __restrict__ bias,
                                               const int* __restrict__ rowptr,
                                               const int* __restrict__ col,
                                               float* __restrict__ out, int nnodes) {
  int wave = threadIdx.x >> 6, lane = threadIdx.x & 63;
  int quarter = lane >> 4, l = lane & 15;
  int sb = lane & 48;
  int n = blockIdx.x * 16 + wave * 4 + quarter;
  bool valid = n < nnodes;
  int beg = 0, end = 0;
  if (valid) {
    beg = rowptr[n];
    end = rowptr[n + 1];
  }
  int co = l * 4;
  const unsigned char* Yc = Y + co;

  f32x2 av0 = {0.f, 0.f}, av1 = {0.f, 0.f};

  for (int base = beg; base < end; base += 16) {
    int cnt = min(end - base, 16);
    int idx = (l < cnt) ? col[base + l] : 0;
    int j = 0;
    for (; j + 3 < cnt; j += 4) {
      long s0 = (unsigned)__shfl(idx, sb + j);
      long s1 = (unsigned)__shfl(idx, sb + j + 1);
      long s2 = (unsigned)__shfl(idx, sb + j + 2);
      long s3 = (unsigned)__shfl(idx, sb + j + 3);
      unsigned v0 = *(const unsigned*)(Yc + s0 * 64);
      unsigned v1 = *(const unsigned*)(Yc + s1 * 64);
      unsigned v2 = *(const unsigned*)(Yc + s2 * 64);
      unsigned v3 = *(const unsigned*)(Yc + s3 * 64);
      av0 += fp8x2_lo(v0); av1 += fp8x2_hi(v0);
      av0 += fp8x2_lo(v1); av1 += fp8x2_hi(v1);
      av0 += fp8x2_lo(v2); av1 += fp8x2_hi(v2);
      av0 += fp8x2_lo(v3); av1 += fp8x2_hi(v3);
    }
    for (; j < cnt; ++j) {
      long s = (unsigned)__shfl(idx, sb + j);
      unsigned v = *(const unsigned*)(Yc + s * 64);
      av0 += fp8x2_lo(v); av1 += fp8x2_hi(v);
    }
  }

  if (valid) {
    float inv = 1.f / (float)max(end - beg, 1);
    bf16x4 xv = *(const bf16x4*)(XR + (long)n * 64 + co);
    f32x4 bv = *(const f32x4*)(bias + co);
    f32x4 r;
    r[0] = av0[0] * inv + (float)xv[0] + bv[0];
    r[1] = av0[1] * inv + (float)xv[1] + bv[1];
    r[2] = av1[0] * inv + (float)xv[2] + bv[2];
    r[3] = av1[1] * inv + (float)xv[3] + bv[3];
    *(f32x4*)(out + (long)n * 64 + co) = r;
  }
}

// ---------------- launch ----------------

extern "C" void kernel_launch(void* const* d_in, const int* in_sizes, int n_in,
                              void* d_out, int out_size, void* d_ws, size_t ws_size,
                              hipStream_t stream) {
  const float* x   = (const float*)d_in[0];
  const int*   ei  = (const int*)d_in[1];
  const float* W1l = (const float*)d_in[2];
  const float* W1r = (const float*)d_in[3];
  const float* b1  = (const float*)d_in[4];
  const float* W2l = (const float*)d_in[5];
  const float* W2r = (const float*)d_in[6];
  const float* b2  = (const float*)d_in[7];
  float* out = (float*)d_out;

  int N = in_sizes[0] / K;   // 100000
  int E = in_sizes[1] / 2;   // 1600000
  const int* src = ei;
  const int* dst = ei + E;

  int nB = (N + 255) >> 8;          // 391 buckets of 256 nodes
  int nblk = (E + EB - 1) / EB;     // 782 partition blocks

  char* ws = (char*)d_ws;
  size_t off = 0;
  auto alloc = [&](size_t bytes) {
    void* p = ws + off;
    off = (off + bytes + 255) & ~(size_t)255;
    return p;
  };
  int*      rowptr      = (int*)alloc(((size_t)N + 2) * 4);
  int*      col         = (int*)alloc((size_t)E * 4);
  int*      bucketCount = (int*)alloc((size_t)nB * 4);
  unsigned* recs        = (unsigned*)alloc((size_t)nB * CAP * 4);
  unsigned char* y1     = (unsigned char*)alloc((size_t)N * 128);  // fp8
  __bf16*   xr          = (__bf16*)alloc((size_t)N * 128 * 2);
  __bf16*   h           = (__bf16*)alloc((size_t)N * 128 * 2);
  unsigned char* y2 = y1;  // layer-1 gather buffer dead after agg128; reuse
  __bf16*   hr = xr;

  int ntiles = (N + 63) / 64;
  int gpers = ntiles < 512 ? ntiles : 512;

  // CSR build: single-pass slotted scatter (782 blocks, 3/CU)
  hipMemsetAsync(bucketCount, 0, (size_t)nB * 4, stream);
  k_scatter<<<nblk, 256, nB * 4, stream>>>(src, dst, bucketCount, recs, E, N, nB);

  // layer 1: y1 = fp8(x@W1l), xr = bf16(x@W1r)
  k_gemm_fused<128, float><<<gpers, 512, 0, stream>>>(x, W1l, W1r, y1, xr, N, ntiles);

  // rowptr/col fill (391 blocks; self-computed bucket prefix), then agg
  k_bfill<<<nB, 256, 0, stream>>>(recs, bucketCount, rowptr, col, N);
  k_agg128<true><<<(N + 15) / 16, 256, 0, stream>>>(y1, xr, b1, rowptr, col, h, N);

  // layer 2: y2 = fp8(h@W2l), hr = bf16(h@W2r)
  k_gemm_fused<64, __bf16><<<gpers, 512, 0, stream>>>(h, W2l, W2r, y2, hr, N, ntiles);

  // out = mean_gather(y2) + hr + b2
  k_agg64<<<(N + 15) / 16, 256, 0, stream>>>(y2, hr, b2, rowptr, col, out, N);
}

// Round 13
// 244.487 us; speedup vs baseline: 1.0223x; 1.0223x over previous
//
#include <hip/hip_runtime.h>
#include <type_traits>

// GraphSAGE 2-layer, N=100k, C 128->128->64, E=1.6M, fp32 in/out.
// R9/R10: latency-optimized quarter-per-node aggregation.
// R11-R15: fused-panel persistent GEMM.
// R16: cooperative mega-kernel FAILED (the coop LAUNCH, not the role-split).
// R17: wprep deleted (direct fp32-B load) — VALIDATED.
// R19: single-pass slotted scatter — 245.7us best.
// R20: EB halving REGRESSED (scatter write amplification); btop deletion
//      kept (neutral, -1 dispatch).
// R21: scatter ∥ gemm1 in ONE ordinary launch via block-role split (no
//      grid.sync: roles are data-independent; bfill afterwards provides
//      the scatter->bfill dependency). Scatter gets 512 threads (2x write
//      TLP) at EB=4096. 6 dispatches.

constexpr int K = 128;
constexpr int EB = 4096;     // edges per partition block (R21: back to best)
constexpr int CAP = 8192;    // slots per bucket (mean 4092, +64 sigma)

typedef __bf16 bf16x2 __attribute__((ext_vector_type(2)));
typedef __bf16 bf16x4 __attribute__((ext_vector_type(4)));
typedef __bf16 bf16x8 __attribute__((ext_vector_type(8)));
typedef float f32x4 __attribute__((ext_vector_type(4)));
typedef float f32x2 __attribute__((ext_vector_type(2)));

// ---------------- fp8 e4m3 conversion ----------------

__device__ __forceinline__ unsigned char to_fp8(float v) {
#if __has_builtin(__builtin_amdgcn_cvt_pk_fp8_f32)
  int p = __builtin_amdgcn_cvt_pk_fp8_f32(v, v, 0, false);
  return (unsigned char)(p & 0xff);
#else
  unsigned u = __builtin_bit_cast(unsigned, v);
  unsigned s = (u >> 24) & 0x80u;
  float a = fabsf(v);
  if (a > 448.f) a = 448.f;
  unsigned bits;
  if (a < 0.015625f) {
    bits = (unsigned)(a * 512.f + 0.5f);
  } else {
    unsigned b = __builtin_bit_cast(unsigned, a);
    b += ((b >> 20) & 1) + 0x0007FFFF;
    unsigned e = (b >> 23) - 120;
    bits = (e << 3) | ((b >> 20) & 7);
    if (bits > 0x7E) bits = 0x7E;
  }
  return (unsigned char)(s | bits);
#endif
}

__device__ __forceinline__ f32x2 from_fp8x2(unsigned short u) {
#if __has_builtin(__builtin_amdgcn_cvt_pk_f32_fp8)
  return __builtin_amdgcn_cvt_pk_f32_fp8((int)u, false);
#else
  f32x2 r;
  unsigned b0 = u & 0xff, b1 = (u >> 8) & 0xff;
  unsigned e0 = (b0 >> 3) & 15, m0 = b0 & 7;
  unsigned e1 = (b1 >> 3) & 15, m1 = b1 & 7;
  float v0 = e0 ? __builtin_bit_cast(float, ((e0 + 120) << 23) | (m0 << 20))
              : (float)m0 * 0.001953125f;
  float v1 = e1 ? __builtin_bit_cast(float, ((e1 + 120) << 23) | (m1 << 20))
              : (float)m1 * 0.001953125f;
  r[0] = (b0 & 0x80) ? -v0 : v0;
  r[1] = (b1 & 0x80) ? -v1 : v1;
  return r;
#endif
}

__device__ __forceinline__ f32x2 fp8x2_lo(unsigned v) {
#if __has_builtin(__builtin_amdgcn_cvt_pk_f32_fp8)
  return __builtin_amdgcn_cvt_pk_f32_fp8((int)v, false);
#else
  return from_fp8x2((unsigned short)(v & 0xffffu));
#endif
}

__device__ __forceinline__ f32x2 fp8x2_hi(unsigned v) {
#if __has_builtin(__builtin_amdgcn_cvt_pk_f32_fp8)
  return __builtin_amdgcn_cvt_pk_f32_fp8((int)v, true);
#else
  return from_fp8x2((unsigned short)(v >> 16));
#endif
}

// ---------------- fused: slotted scatter (blocks 0..nscat-1) ∥ GEMM1 ----------
// No grid.sync: the two roles touch disjoint data. Dispatch order puts
// scatter blocks first (critical path to bfill). LDS: GEMM needs
// 2x64x136 bf16 = 34.8KB; scatter aliases the first nB ints of it.

template <int COLS>
__global__ __launch_bounds__(512, 4) void k_scatter_gemm(
    // scatter args
    const int* __restrict__ src, const int* __restrict__ dst,
    int* __restrict__ bucketCount, unsigned* __restrict__ recs,
    int E, int n, int nB, int nscat,
    // gemm args
    const float* __restrict__ X, const float* __restrict__ Wa,
    const float* __restrict__ Wb, unsigned char* __restrict__ outA,
    __bf16* __restrict__ outB, int ntiles) {
  constexpr int LD = 136;
  constexpr int NI = COLS / 64;
  __shared__ __bf16 As[2][64 * LD];

  int bid = blockIdx.x;
  int tid = threadIdx.x;

  if (bid < nscat) {
    // ---------------- scatter role ----------------
    int* cur = (int*)As;
    for (int i = tid; i < nB; i += 512) cur[i] = 0;
    __syncthreads();
    int base = bid * EB, endE = min(base + EB, E);
    for (int e = base + tid; e < endE; e += 512) {
      int d = dst[e];
      if ((unsigned)d < (unsigned)n) atomicAdd(&cur[d >> 8], 1);
    }
    __syncthreads();
    for (int i = tid; i < nB; i += 512) {
      int c = cur[i];
      cur[i] = c ? atomicAdd(&bucketCount[i], c) : 0;
    }
    __syncthreads();
    for (int e = base + tid; e < endE; e += 512) {
      int d = dst[e];
      if ((unsigned)d < (unsigned)n) {
        int s = min(max(src[e], 0), n - 1);
        int b = d >> 8;
        int pos = min(atomicAdd(&cur[b], 1), CAP - 1);  // clamp: OOB-safe
        recs[(long)b * CAP + pos] = ((unsigned)s << 8) | (unsigned)(d & 255);
      }
    }
    return;
  }

  // ---------------- GEMM1 role (persistent, fused panels, direct fp32 B) ----
  int w = tid >> 6, lane = tid & 63;
  int m = lane & 15, quad = lane >> 4;
  int panel = w >> 2;
  int wcol = (w & 3) * (16 * NI);
  const float* Wsrc = panel ? Wb : Wa;

  bf16x8 bq[4][NI];
#pragma unroll
  for (int kc = 0; kc < 4; ++kc)
#pragma unroll
    for (int ni = 0; ni < NI; ++ni)
#pragma unroll
      for (int e = 0; e < 8; ++e)
        bq[kc][ni][e] = (__bf16)Wsrc[(kc * 32 + quad * 8 + e) * COLS + (wcol + ni * 16 + m)];

  float4 ra[4];
  auto load_tile = [&](int t) {
    long row0 = (long)t * 64;
#pragma unroll
    for (int it = 0; it < 4; ++it) {
      int i = tid + it * 512;
      int r = i >> 5, c4 = (i & 31) << 2;
      long row = row0 + r;
      float4 v = make_float4(0.f, 0.f, 0.f, 0.f);
      if (row < n) v = *(const float4*)(X + row * K + c4);
      ra[it] = v;
    }
  };
  auto write_tile = [&](int buf) {
#pragma unroll
    for (int it = 0; it < 4; ++it) {
      int i = tid + it * 512;
      int r = i >> 5, c4 = (i & 31) << 2;
      bf16x4 bb;
      bb[0] = (__bf16)ra[it].x; bb[1] = (__bf16)ra[it].y;
      bb[2] = (__bf16)ra[it].z; bb[3] = (__bf16)ra[it].w;
      *(bf16x4*)&As[buf][r * LD + c4] = bb;
    }
  };

  int t = bid - nscat;
  int stride = (int)gridDim.x - nscat;
  if (t < ntiles) load_tile(t);

#pragma unroll
  for (int kc = 0; kc < 4; ++kc)
#pragma unroll
    for (int ni = 0; ni < NI; ++ni)
      asm volatile("" :: "v"(bq[kc][ni]));

  int buf = 0;
  while (t < ntiles) {
    write_tile(buf);
    __syncthreads();
    int tn = t + stride;
    if (tn < ntiles) load_tile(tn);  // prefetch under compute

    f32x4 acc[4][NI];
#pragma unroll
    for (int mi = 0; mi < 4; ++mi)
#pragma unroll
      for (int ni = 0; ni < NI; ++ni) acc[mi][ni] = (f32x4){0.f, 0.f, 0.f, 0.f};

#pragma unroll
    for (int kc = 0; kc < 4; ++kc) {
      int ko = kc * 32 + quad * 8;
      bf16x8 af[4];
#pragma unroll
      for (int mi = 0; mi < 4; ++mi)
        af[mi] = *(const bf16x8*)&As[buf][(mi * 16 + m) * LD + ko];
#pragma unroll
      for (int mi = 0; mi < 4; ++mi)
#pragma unroll
        for (int ni = 0; ni < NI; ++ni)
          acc[mi][ni] = __builtin_amdgcn_mfma_f32_16x16x32_bf16(af[mi], bq[kc][ni], acc[mi][ni], 0, 0, 0);
    }

    long row0 = (long)t * 64;
#pragma unroll
    for (int mi = 0; mi < 4; ++mi) {
#pragma unroll
      for (int r = 0; r < 4; ++r) {
        long grow = row0 + mi * 16 + quad * 4 + r;
        if (grow < n) {
#pragma unroll
          for (int ni = 0; ni < NI; ++ni) {
            long idx = grow * COLS + wcol + ni * 16 + m;
            float v = acc[mi][ni][r];
            if (panel == 0) outA[idx] = to_fp8(v);
            else            outB[idx] = (__bf16)v;
          }
        }
      }
    }
    t = tn;
    buf ^= 1;
  }
}

// Per-bucket rowptr + col fill from the slotted recs region; computes its
// own bucket prefix (masked reduce over bucketCount).
__global__ __launch_bounds__(256) void k_bfill(const unsigned* __restrict__ recs,
                                               const int* __restrict__ bucketCount,
                                               int* __restrict__ rowptr,
                                               int* __restrict__ col, int n) {
  __shared__ int degl[256];
  __shared__ int incl[256];
  __shared__ int red[256];
  int b = blockIdx.x, t = threadIdx.x;

  int partial = 0;
  for (int i = t; i < b; i += 256) partial += bucketCount[i];
  red[t] = partial;
  __syncthreads();
  for (int off = 128; off > 0; off >>= 1) {
    if (t < off) red[t] += red[t + off];
    __syncthreads();
  }
  int rbeg = red[0];
  int cnt = bucketCount[b];
  const unsigned* rbase = recs + (long)b * CAP;
  __syncthreads();

  degl[t] = 0;
  __syncthreads();
  for (int i = t; i < cnt; i += 256)
    atomicAdd(&degl[rbase[i] & 255], 1);
  __syncthreads();
  incl[t] = degl[t];
  __syncthreads();
  for (int off = 1; off < 256; off <<= 1) {
    int v = (t >= off) ? incl[t - off] : 0;
    __syncthreads();
    incl[t] += v;
    __syncthreads();
  }
  int excl = incl[t] - degl[t];
  int node = b * 256 + t;
  if (node <= n) rowptr[node] = rbeg + excl;
  __syncthreads();
  degl[t] = rbeg + excl;  // reuse as cursor
  __syncthreads();
  for (int i = t; i < cnt; i += 256) {
    unsigned r = rbase[i];
    int pos = atomicAdd(&degl[r & 255], 1);
    col[pos] = (int)(r >> 8);
  }
}

// ---------------- layer-2 GEMM (persistent, fused panels, direct fp32 B) ------

template <int COLS, typename TIN>
__global__ __launch_bounds__(512, 4) void k_gemm_fused(const TIN* __restrict__ X,
                                                       const float* __restrict__ Wa,
                                                       const float* __restrict__ Wb,
                                                       unsigned char* __restrict__ outA,
                                                       __bf16* __restrict__ outB,
                                                       int nrows, int ntiles) {
  constexpr int LD = 136;
  constexpr int NI = COLS / 64;
  constexpr bool FP32IN = std::is_same_v<TIN, float>;
  __shared__ __bf16 As[2][64 * LD];

  int tid = threadIdx.x;
  int w = tid >> 6, lane = tid & 63;
  int m = lane & 15, quad = lane >> 4;
  int panel = w >> 2;
  int wcol = (w & 3) * (16 * NI);
  const float* Wsrc = panel ? Wb : Wa;

  bf16x8 bq[4][NI];
#pragma unroll
  for (int kc = 0; kc < 4; ++kc)
#pragma unroll
    for (int ni = 0; ni < NI; ++ni)
#pragma unroll
      for (int e = 0; e < 8; ++e)
        bq[kc][ni][e] = (__bf16)Wsrc[(kc * 32 + quad * 8 + e) * COLS + (wcol + ni * 16 + m)];

  float4 ra[4];
  bf16x8 rb[2];

  auto load_tile = [&](int t) {
    long row0 = (long)t * 64;
    if constexpr (FP32IN) {
#pragma unroll
      for (int it = 0; it < 4; ++it) {
        int i = tid + it * 512;
        int r = i >> 5, c4 = (i & 31) << 2;
        long row = row0 + r;
        float4 v = make_float4(0.f, 0.f, 0.f, 0.f);
        if (row < nrows) v = *(const float4*)(X + row * K + c4);
        ra[it] = v;
      }
    } else {
#pragma unroll
      for (int it = 0; it < 2; ++it) {
        int i = tid + it * 512;
        int r = i >> 4, c8 = (i & 15) << 3;
        long row = row0 + r;
        bf16x8 v = {};
        if (row < nrows) v = *(const bf16x8*)(X + row * K + c8);
        rb[it] = v;
      }
    }
  };

  auto write_tile = [&](int buf) {
    if constexpr (FP32IN) {
#pragma unroll
      for (int it = 0; it < 4; ++it) {
        int i = tid + it * 512;
        int r = i >> 5, c4 = (i & 31) << 2;
        bf16x4 bb;
        bb[0] = (__bf16)ra[it].x; bb[1] = (__bf16)ra[it].y;
        bb[2] = (__bf16)ra[it].z; bb[3] = (__bf16)ra[it].w;
        *(bf16x4*)&As[buf][r * LD + c4] = bb;
      }
    } else {
#pragma unroll
      for (int it = 0; it < 2; ++it) {
        int i = tid + it * 512;
        int r = i >> 4, c8 = (i & 15) << 3;
        *(bf16x8*)&As[buf][r * LD + c8] = rb[it];
      }
    }
  };

  int t = (int)blockIdx.x;
  int stride = (int)gridDim.x;
  if (t < ntiles) load_tile(t);

#pragma unroll
  for (int kc = 0; kc < 4; ++kc)
#pragma unroll
    for (int ni = 0; ni < NI; ++ni)
      asm volatile("" :: "v"(bq[kc][ni]));

  int buf = 0;
  while (t < ntiles) {
    write_tile(buf);
    __syncthreads();
    int tn = t + stride;
    if (tn < ntiles) load_tile(tn);  // prefetch under compute

    f32x4 acc[4][NI];
#pragma unroll
    for (int mi = 0; mi < 4; ++mi)
#pragma unroll
      for (int ni = 0; ni < NI; ++ni) acc[mi][ni] = (f32x4){0.f, 0.f, 0.f, 0.f};

#pragma unroll
    for (int kc = 0; kc < 4; ++kc) {
      int ko = kc * 32 + quad * 8;
      bf16x8 af[4];
#pragma unroll
      for (int mi = 0; mi < 4; ++mi)
        af[mi] = *(const bf16x8*)&As[buf][(mi * 16 + m) * LD + ko];
#pragma unroll
      for (int mi = 0; mi < 4; ++mi)
#pragma unroll
        for (int ni = 0; ni < NI; ++ni)
          acc[mi][ni] = __builtin_amdgcn_mfma_f32_16x16x32_bf16(af[mi], bq[kc][ni], acc[mi][ni], 0, 0, 0);
    }

    long row0 = (long)t * 64;
#pragma unroll
    for (int mi = 0; mi < 4; ++mi) {
#pragma unroll
      for (int r = 0; r < 4; ++r) {
        long grow = row0 + mi * 16 + quad * 4 + r;
        if (grow < nrows) {
#pragma unroll
          for (int ni = 0; ni < NI; ++ni) {
            long idx = grow * COLS + wcol + ni * 16 + m;
            float v = acc[mi][ni][r];
            if (panel == 0) outA[idx] = to_fp8(v);
            else            outB[idx] = (__bf16)v;
          }
        }
      }
    }
    t = tn;
    buf ^= 1;
  }
}

// ---------------- aggregation (proven R10 structure, full grids) ----------------

template <bool RELU>
__global__ __launch_bounds__(256) void k_agg128(const unsigned char* __restrict__ Y,
                                                const __bf16* __restrict__ XR,
                                                const float* __restrict__ bias,
                                                const int* __restrict__ rowptr,
                                                const int* __restrict__ col,
                                                __bf16* __restrict__ out, int nnodes) {
  int wave = threadIdx.x >> 6, lane = threadIdx.x & 63;
  int quarter = lane >> 4, l = lane & 15;
  int sb = lane & 48;
  int n = blockIdx.x * 16 + wave * 4 + quarter;
  bool valid = n < nnodes;
  int beg = 0, end = 0;
  if (valid) {
    beg = rowptr[n];
    end = rowptr[n + 1];
  }
  int co = l * 8;
  const unsigned char* Yc = Y + co;

  f32x2 av0 = {0.f, 0.f}, av1 = {0.f, 0.f}, av2 = {0.f, 0.f}, av3 = {0.f, 0.f};

  for (int base = beg; base < end; base += 16) {
    int cnt = min(end - base, 16);
    int idx = (l < cnt) ? col[base + l] : 0;
    int j = 0;
    for (; j + 3 < cnt; j += 4) {
      long s0 = (unsigned)__shfl(idx, sb + j);
      long s1 = (unsigned)__shfl(idx, sb + j + 1);
      long s2 = (unsigned)__shfl(idx, sb + j + 2);
      long s3 = (unsigned)__shfl(idx, sb + j + 3);
      uint2 v0 = *(const uint2*)(Yc + s0 * 128);
      uint2 v1 = *(const uint2*)(Yc + s1 * 128);
      uint2 v2 = *(const uint2*)(Yc + s2 * 128);
      uint2 v3 = *(const uint2*)(Yc + s3 * 128);
      av0 += fp8x2_lo(v0.x); av1 += fp8x2_hi(v0.x);
      av2 += fp8x2_lo(v0.y); av3 += fp8x2_hi(v0.y);
      av0 += fp8x2_lo(v1.x); av1 += fp8x2_hi(v1.x);
      av2 += fp8x2_lo(v1.y); av3 += fp8x2_hi(v1.y);
      av0 += fp8x2_lo(v2.x); av1 += fp8x2_hi(v2.x);
      av2 += fp8x2_lo(v2.y); av3 += fp8x2_hi(v2.y);
      av0 += fp8x2_lo(v3.x); av1 += fp8x2_hi(v3.x);
      av2 += fp8x2_lo(v3.y); av3 += fp8x2_hi(v3.y);
    }
    for (; j < cnt; ++j) {
      long s = (unsigned)__shfl(idx, sb + j);
      uint2 v = *(const uint2*)(Yc + s * 128);
      av0 += fp8x2_lo(v.x); av1 += fp8x2_hi(v.x);
      av2 += fp8x2_lo(v.y); av3 += fp8x2_hi(v.y);
    }
  }

  if (valid) {
    float inv = 1.f / (float)max(end - beg, 1);
    bf16x8 xv = *(const bf16x8*)(XR + (long)n * 128 + co);
    f32x4 b0 = *(const f32x4*)(bias + co);
    f32x4 b1 = *(const f32x4*)(bias + co + 4);
    float r0 = av0[0] * inv + (float)xv[0] + b0[0];
    float r1 = av0[1] * inv + (float)xv[1] + b0[1];
    float r2 = av1[0] * inv + (float)xv[2] + b0[2];
    float r3 = av1[1] * inv + (float)xv[3] + b0[3];
    float r4 = av2[0] * inv + (float)xv[4] + b1[0];
    float r5 = av2[1] * inv + (float)xv[5] + b1[1];
    float r6 = av3[0] * inv + (float)xv[6] + b1[2];
    float r7 = av3[1] * inv + (float)xv[7] + b1[3];
    if (RELU) {
      r0 = fmaxf(r0, 0.f); r1 = fmaxf(r1, 0.f);
      r2 = fmaxf(r2, 0.f); r3 = fmaxf(r3, 0.f);
      r4 = fmaxf(r4, 0.f); r5 = fmaxf(r5, 0.f);
      r6 = fmaxf(r6, 0.f); r7 = fmaxf(r7, 0.f);
    }
    bf16x8 o;
    o[0] = (__bf16)r0; o[1] = (__bf16)r1; o[2] = (__bf16)r2; o[3] = (__bf16)r3;
    o[4] = (__bf16)r4; o[5] = (__bf16)r5; o[6] = (__bf16)r6; o[7] = (__bf16)r7;
    *(bf16x8*)(out + (long)n * 128 + co) = o;
  }
}

__global__ __launch_bounds__(256) void k_agg64(const unsigned char* __restrict__ Y,
                                               const __bf16* __restrict__ XR,
                                               const float* __restrict__ bias,
                                               const int* __restrict__ rowptr,
                                               const int* __restrict__ col,
                                               float* __restrict__ out, int nnodes) {
  int wave = threadIdx.x >> 6, lane = threadIdx.x & 63;
  int quarter = lane >> 4, l = lane & 15;
  int sb = lane & 48;
  int n = blockIdx.x * 16 + wave * 4 + quarter;
  bool valid = n < nnodes;
  int beg = 0, end = 0;
  if (valid) {
    beg = rowptr[n];
    end = rowptr[n + 1];
  }
  int co = l * 4;
  const unsigned char* Yc = Y + co;

  f32x2 av0 = {0.f, 0.f}, av1 = {0.f, 0.f};

  for (int base = beg; base < end; base += 16) {
    int cnt = min(end - base, 16);
    int idx = (l < cnt) ? col[base + l] : 0;
    int j = 0;
    for (; j + 3 < cnt; j += 4) {
      long s0 = (unsigned)__shfl(idx, sb + j);
      long s1 = (unsigned)__shfl(idx, sb + j + 1);
      long s2 = (unsigned)__shfl(idx, sb + j + 2);
      long s3 = (unsigned)__shfl(idx, sb + j + 3);
      unsigned v0 = *(const unsigned*)(Yc + s0 * 64);
      unsigned v1 = *(const unsigned*)(Yc + s1 * 64);
      unsigned v2 = *(const unsigned*)(Yc + s2 * 64);
      unsigned v3 = *(const unsigned*)(Yc + s3 * 64);
      av0 += fp8x2_lo(v0); av1 += fp8x2_hi(v0);
      av0 += fp8x2_lo(v1); av1 += fp8x2_hi(v1);
      av0 += fp8x2_lo(v2); av1 += fp8x2_hi(v2);
      av0 += fp8x2_lo(v3); av1 += fp8x2_hi(v3);
    }
    for (; j < cnt; ++j) {
      long s = (unsigned)__shfl(idx, sb + j);
      unsigned v = *(const unsigned*)(Yc + s * 64);
      av0 += fp8x2_lo(v); av1 += fp8x2_hi(v);
    }
  }

  if (valid) {
    float inv = 1.f / (float)max(end - beg, 1);
    bf16x4 xv = *(const bf16x4*)(XR + (long)n * 64 + co);
    f32x4 bv = *(const f32x4*)(bias + co);
    f32x4 r;
    r[0] = av0[0] * inv + (float)xv[0] + bv[0];
    r[1] = av0[1] * inv + (float)xv[1] + bv[1];
    r[2] = av1[0] * inv + (float)xv[2] + bv[2];
    r[3] = av1[1] * inv + (float)xv[3] + bv[3];
    *(f32x4*)(out + (long)n * 64 + co) = r;
  }
}

// ---------------- launch ----------------

extern "C" void kernel_launch(void* const* d_in, const int* in_sizes, int n_in,
                              void* d_out, int out_size, void* d_ws, size_t ws_size,
                              hipStream_t stream) {
  const float* x   = (const float*)d_in[0];
  const int*   ei  = (const int*)d_in[1];
  const float* W1l = (const float*)d_in[2];
  const float* W1r = (const float*)d_in[3];
  const float* b1  = (const float*)d_in[4];
  const float* W2l = (const float*)d_in[5];
  const float* W2r = (const float*)d_in[6];
  const float* b2  = (const float*)d_in[7];
  float* out = (float*)d_out;

  int N = in_sizes[0] / K;   // 100000
  int E = in_sizes[1] / 2;   // 1600000
  const int* src = ei;
  const int* dst = ei + E;

  int nB = (N + 255) >> 8;          // 391 buckets of 256 nodes
  int nblk = (E + EB - 1) / EB;     // 391 scatter blocks

  char* ws = (char*)d_ws;
  size_t off = 0;
  auto alloc = [&](size_t bytes) {
    void* p = ws + off;
    off = (off + bytes + 255) & ~(size_t)255;
    return p;
  };
  int*      rowptr      = (int*)alloc(((size_t)N + 2) * 4);
  int*      col         = (int*)alloc((size_t)E * 4);
  int*      bucketCount = (int*)alloc((size_t)nB * 4);
  unsigned* recs        = (unsigned*)alloc((size_t)nB * CAP * 4);
  unsigned char* y1     = (unsigned char*)alloc((size_t)N * 128);  // fp8
  __bf16*   xr          = (__bf16*)alloc((size_t)N * 128 * 2);
  __bf16*   h           = (__bf16*)alloc((size_t)N * 128 * 2);
  unsigned char* y2 = y1;  // layer-1 gather buffer dead after agg128; reuse
  __bf16*   hr = xr;

  int ntiles = (N + 63) / 64;
  int gpers = ntiles < 512 ? ntiles : 512;

  // fused: scatter (blocks 0..nblk-1) ∥ layer-1 GEMM (blocks nblk..)
  hipMemsetAsync(bucketCount, 0, (size_t)nB * 4, stream);
  k_scatter_gemm<128><<<nblk + gpers, 512, 0, stream>>>(
      src, dst, bucketCount, recs, E, N, nB, nblk,
      x, W1l, W1r, y1, xr, ntiles);

  // rowptr/col fill (391 blocks; self-computed bucket prefix), then agg
  k_bfill<<<nB, 256, 0, stream>>>(recs, bucketCount, rowptr, col, N);
  k_agg128<true><<<(N + 15) / 16, 256, 0, stream>>>(y1, xr, b1, rowptr, col, h, N);

  // layer 2: y2 = fp8(h@W2l), hr = bf16(h@W2r)
  k_gemm_fused<64, __bf16><<<gpers, 512, 0, stream>>>(h, W2l, W2r, y2, hr, N, ntiles);

  // out = mean_gather(y2) + hr + b2
  k_agg64<<<(N + 15) / 16, 256, 0, stream>>>(y2, hr, b2, rowptr, col, out, N);
}

// Round 14
// 240.020 us; speedup vs baseline: 1.0414x; 1.0186x over previous
//
#include <hip/hip_runtime.h>
#include <type_traits>

// GraphSAGE 2-layer, N=100k, C 128->128->64, E=1.6M, fp32 in/out.
// R9/R10: latency-optimized quarter-per-node aggregation.
// R11-R15: fused-panel persistent GEMM.
// R17: wprep deleted (direct fp32-B load) — VALIDATED.
// R19: single-pass slotted scatter — 245.7us.
// R21: scatter ∥ gemm1 block-role split in one launch — 244.5us BEST.
// R22: dynamic tile work-queue (global atomic tileCtr): scatter blocks
//      fall through into the GEMM role after their edge chunk -> the
//      scatter tail becomes GEMM throughput; no static-stride imbalance.
//      tileCtr shares the zeroed metadata block with bucketCount.

constexpr int K = 128;
constexpr int EB = 4096;     // edges per scatter block
constexpr int CAP = 8192;    // slots per bucket (mean 4092, +64 sigma)

typedef __bf16 bf16x2 __attribute__((ext_vector_type(2)));
typedef __bf16 bf16x4 __attribute__((ext_vector_type(4)));
typedef __bf16 bf16x8 __attribute__((ext_vector_type(8)));
typedef float f32x4 __attribute__((ext_vector_type(4)));
typedef float f32x2 __attribute__((ext_vector_type(2)));

// ---------------- fp8 e4m3 conversion ----------------

__device__ __forceinline__ unsigned char to_fp8(float v) {
#if __has_builtin(__builtin_amdgcn_cvt_pk_fp8_f32)
  int p = __builtin_amdgcn_cvt_pk_fp8_f32(v, v, 0, false);
  return (unsigned char)(p & 0xff);
#else
  unsigned u = __builtin_bit_cast(unsigned, v);
  unsigned s = (u >> 24) & 0x80u;
  float a = fabsf(v);
  if (a > 448.f) a = 448.f;
  unsigned bits;
  if (a < 0.015625f) {
    bits = (unsigned)(a * 512.f + 0.5f);
  } else {
    unsigned b = __builtin_bit_cast(unsigned, a);
    b += ((b >> 20) & 1) + 0x0007FFFF;
    unsigned e = (b >> 23) - 120;
    bits = (e << 3) | ((b >> 20) & 7);
    if (bits > 0x7E) bits = 0x7E;
  }
  return (unsigned char)(s | bits);
#endif
}

__device__ __forceinline__ f32x2 from_fp8x2(unsigned short u) {
#if __has_builtin(__builtin_amdgcn_cvt_pk_f32_fp8)
  return __builtin_amdgcn_cvt_pk_f32_fp8((int)u, false);
#else
  f32x2 r;
  unsigned b0 = u & 0xff, b1 = (u >> 8) & 0xff;
  unsigned e0 = (b0 >> 3) & 15, m0 = b0 & 7;
  unsigned e1 = (b1 >> 3) & 15, m1 = b1 & 7;
  float v0 = e0 ? __builtin_bit_cast(float, ((e0 + 120) << 23) | (m0 << 20))
              : (float)m0 * 0.001953125f;
  float v1 = e1 ? __builtin_bit_cast(float, ((e1 + 120) << 23) | (m1 << 20))
              : (float)m1 * 0.001953125f;
  r[0] = (b0 & 0x80) ? -v0 : v0;
  r[1] = (b1 & 0x80) ? -v1 : v1;
  return r;
#endif
}

__device__ __forceinline__ f32x2 fp8x2_lo(unsigned v) {
#if __has_builtin(__builtin_amdgcn_cvt_pk_f32_fp8)
  return __builtin_amdgcn_cvt_pk_f32_fp8((int)v, false);
#else
  return from_fp8x2((unsigned short)(v & 0xffffu));
#endif
}

__device__ __forceinline__ f32x2 fp8x2_hi(unsigned v) {
#if __has_builtin(__builtin_amdgcn_cvt_pk_f32_fp8)
  return __builtin_amdgcn_cvt_pk_f32_fp8((int)v, true);
#else
  return from_fp8x2((unsigned short)(v >> 16));
#endif
}

// ---------------- fused: slotted scatter -> GEMM1 (dynamic tile queue) --------
// Blocks 0..nscat-1 scatter their edge chunk FIRST, then fall through into
// the GEMM role. GEMM tiles are popped from a global atomic counter, so
// late-joining scatter blocks load-balance automatically. No grid.sync:
// roles touch disjoint data; the next dispatch (bfill) is the sync point.

template <int COLS>
__global__ __launch_bounds__(512, 4) void k_scatter_gemm(
    // scatter args
    const int* __restrict__ src, const int* __restrict__ dst,
    int* __restrict__ bucketCount, unsigned* __restrict__ recs,
    int E, int n, int nB, int nscat,
    // gemm args
    int* __restrict__ tileCtr, const float* __restrict__ X,
    const float* __restrict__ Wa, const float* __restrict__ Wb,
    unsigned char* __restrict__ outA, __bf16* __restrict__ outB, int ntiles) {
  constexpr int LD = 136;
  constexpr int NI = COLS / 64;
  __shared__ __bf16 As[2][64 * LD];
  __shared__ int shT;

  int bid = blockIdx.x;
  int tid = threadIdx.x;

  if (bid < nscat) {
    // ---------------- scatter role ----------------
    int* cur = (int*)As;
    for (int i = tid; i < nB; i += 512) cur[i] = 0;
    __syncthreads();
    int base = bid * EB, endE = min(base + EB, E);
    for (int e = base + tid; e < endE; e += 512) {
      int d = dst[e];
      if ((unsigned)d < (unsigned)n) atomicAdd(&cur[d >> 8], 1);
    }
    __syncthreads();
    for (int i = tid; i < nB; i += 512) {
      int c = cur[i];
      cur[i] = c ? atomicAdd(&bucketCount[i], c) : 0;
    }
    __syncthreads();
    for (int e = base + tid; e < endE; e += 512) {
      int d = dst[e];
      if ((unsigned)d < (unsigned)n) {
        int s = min(max(src[e], 0), n - 1);
        int b = d >> 8;
        int pos = min(atomicAdd(&cur[b], 1), CAP - 1);  // clamp: OOB-safe
        recs[(long)b * CAP + pos] = ((unsigned)s << 8) | (unsigned)(d & 255);
      }
    }
    __syncthreads();  // LDS (cur aliases As) free before GEMM reuse
    // fall through into GEMM role
  }

  // ---------------- GEMM1 role (dynamic-queue persistent) ----------------
  int w = tid >> 6, lane = tid & 63;
  int m = lane & 15, quad = lane >> 4;
  int panel = w >> 2;
  int wcol = (w & 3) * (16 * NI);
  const float* Wsrc = panel ? Wb : Wa;

  bf16x8 bq[4][NI];
#pragma unroll
  for (int kc = 0; kc < 4; ++kc)
#pragma unroll
    for (int ni = 0; ni < NI; ++ni)
#pragma unroll
      for (int e = 0; e < 8; ++e)
        bq[kc][ni][e] = (__bf16)Wsrc[(kc * 32 + quad * 8 + e) * COLS + (wcol + ni * 16 + m)];

  float4 ra[4];
  auto load_tile = [&](int t) {
    long row0 = (long)t * 64;
#pragma unroll
    for (int it = 0; it < 4; ++it) {
      int i = tid + it * 512;
      int r = i >> 5, c4 = (i & 31) << 2;
      long row = row0 + r;
      float4 v = make_float4(0.f, 0.f, 0.f, 0.f);
      if (row < n) v = *(const float4*)(X + row * K + c4);
      ra[it] = v;
    }
  };
  auto write_tile = [&](int buf) {
#pragma unroll
    for (int it = 0; it < 4; ++it) {
      int i = tid + it * 512;
      int r = i >> 5, c4 = (i & 31) << 2;
      bf16x4 bb;
      bb[0] = (__bf16)ra[it].x; bb[1] = (__bf16)ra[it].y;
      bb[2] = (__bf16)ra[it].z; bb[3] = (__bf16)ra[it].w;
      *(bf16x4*)&As[buf][r * LD + c4] = bb;
    }
  };

  // pop first tile
  if (tid == 0) shT = atomicAdd(tileCtr, 1);
  __syncthreads();
  int t = shT;
  if (t < ntiles) load_tile(t);

#pragma unroll
  for (int kc = 0; kc < 4; ++kc)
#pragma unroll
    for (int ni = 0; ni < NI; ++ni)
      asm volatile("" :: "v"(bq[kc][ni]));

  int buf = 0;
  while (t < ntiles) {
    write_tile(buf);
    __syncthreads();                 // LDS A ready; also orders shT reuse
    if (tid == 0) shT = atomicAdd(tileCtr, 1);
    __syncthreads();
    int tn = shT;
    if (tn < ntiles) load_tile(tn);  // prefetch under compute

    f32x4 acc[4][NI];
#pragma unroll
    for (int mi = 0; mi < 4; ++mi)
#pragma unroll
      for (int ni = 0; ni < NI; ++ni) acc[mi][ni] = (f32x4){0.f, 0.f, 0.f, 0.f};

#pragma unroll
    for (int kc = 0; kc < 4; ++kc) {
      int ko = kc * 32 + quad * 8;
      bf16x8 af[4];
#pragma unroll
      for (int mi = 0; mi < 4; ++mi)
        af[mi] = *(const bf16x8*)&As[buf][(mi * 16 + m) * LD + ko];
#pragma unroll
      for (int mi = 0; mi < 4; ++mi)
#pragma unroll
        for (int ni = 0; ni < NI; ++ni)
          acc[mi][ni] = __builtin_amdgcn_mfma_f32_16x16x32_bf16(af[mi], bq[kc][ni], acc[mi][ni], 0, 0, 0);
    }

    long row0 = (long)t * 64;
#pragma unroll
    for (int mi = 0; mi < 4; ++mi) {
#pragma unroll
      for (int r = 0; r < 4; ++r) {
        long grow = row0 + mi * 16 + quad * 4 + r;
        if (grow < n) {
#pragma unroll
          for (int ni = 0; ni < NI; ++ni) {
            long idx = grow * COLS + wcol + ni * 16 + m;
            float v = acc[mi][ni][r];
            if (panel == 0) outA[idx] = to_fp8(v);
            else            outB[idx] = (__bf16)v;
          }
        }
      }
    }
    t = tn;
    buf ^= 1;
  }
}

// Per-bucket rowptr + col fill from the slotted recs region; computes its
// own bucket prefix (masked reduce over bucketCount).
__global__ __launch_bounds__(256) void k_bfill(const unsigned* __restrict__ recs,
                                               const int* __restrict__ bucketCount,
                                               int* __restrict__ rowptr,
                                               int* __restrict__ col, int n) {
  __shared__ int degl[256];
  __shared__ int incl[256];
  __shared__ int red[256];
  int b = blockIdx.x, t = threadIdx.x;

  int partial = 0;
  for (int i = t; i < b; i += 256) partial += bucketCount[i];
  red[t] = partial;
  __syncthreads();
  for (int off = 128; off > 0; off >>= 1) {
    if (t < off) red[t] += red[t + off];
    __syncthreads();
  }
  int rbeg = red[0];
  int cnt = bucketCount[b];
  const unsigned* rbase = recs + (long)b * CAP;
  __syncthreads();

  degl[t] = 0;
  __syncthreads();
  for (int i = t; i < cnt; i += 256)
    atomicAdd(&degl[rbase[i] & 255], 1);
  __syncthreads();
  incl[t] = degl[t];
  __syncthreads();
  for (int off = 1; off < 256; off <<= 1) {
    int v = (t >= off) ? incl[t - off] : 0;
    __syncthreads();
    incl[t] += v;
    __syncthreads();
  }
  int excl = incl[t] - degl[t];
  int node = b * 256 + t;
  if (node <= n) rowptr[node] = rbeg + excl;
  __syncthreads();
  degl[t] = rbeg + excl;  // reuse as cursor
  __syncthreads();
  for (int i = t; i < cnt; i += 256) {
    unsigned r = rbase[i];
    int pos = atomicAdd(&degl[r & 255], 1);
    col[pos] = (int)(r >> 8);
  }
}

// ---------------- layer-2 GEMM (persistent, fused panels, direct fp32 B) ------

template <int COLS, typename TIN>
__global__ __launch_bounds__(512, 4) void k_gemm_fused(const TIN* __restrict__ X,
                                                       const float* __restrict__ Wa,
                                                       const float* __restrict__ Wb,
                                                       unsigned char* __restrict__ outA,
                                                       __bf16* __restrict__ outB,
                                                       int nrows, int ntiles) {
  constexpr int LD = 136;
  constexpr int NI = COLS / 64;
  constexpr bool FP32IN = std::is_same_v<TIN, float>;
  __shared__ __bf16 As[2][64 * LD];

  int tid = threadIdx.x;
  int w = tid >> 6, lane = tid & 63;
  int m = lane & 15, quad = lane >> 4;
  int panel = w >> 2;
  int wcol = (w & 3) * (16 * NI);
  const float* Wsrc = panel ? Wb : Wa;

  bf16x8 bq[4][NI];
#pragma unroll
  for (int kc = 0; kc < 4; ++kc)
#pragma unroll
    for (int ni = 0; ni < NI; ++ni)
#pragma unroll
      for (int e = 0; e < 8; ++e)
        bq[kc][ni][e] = (__bf16)Wsrc[(kc * 32 + quad * 8 + e) * COLS + (wcol + ni * 16 + m)];

  float4 ra[4];
  bf16x8 rb[2];

  auto load_tile = [&](int t) {
    long row0 = (long)t * 64;
    if constexpr (FP32IN) {
#pragma unroll
      for (int it = 0; it < 4; ++it) {
        int i = tid + it * 512;
        int r = i >> 5, c4 = (i & 31) << 2;
        long row = row0 + r;
        float4 v = make_float4(0.f, 0.f, 0.f, 0.f);
        if (row < nrows) v = *(const float4*)(X + row * K + c4);
        ra[it] = v;
      }
    } else {
#pragma unroll
      for (int it = 0; it < 2; ++it) {
        int i = tid + it * 512;
        int r = i >> 4, c8 = (i & 15) << 3;
        long row = row0 + r;
        bf16x8 v = {};
        if (row < nrows) v = *(const bf16x8*)(X + row * K + c8);
        rb[it] = v;
      }
    }
  };

  auto write_tile = [&](int buf) {
    if constexpr (FP32IN) {
#pragma unroll
      for (int it = 0; it < 4; ++it) {
        int i = tid + it * 512;
        int r = i >> 5, c4 = (i & 31) << 2;
        bf16x4 bb;
        bb[0] = (__bf16)ra[it].x; bb[1] = (__bf16)ra[it].y;
        bb[2] = (__bf16)ra[it].z; bb[3] = (__bf16)ra[it].w;
        *(bf16x4*)&As[buf][r * LD + c4] = bb;
      }
    } else {
#pragma unroll
      for (int it = 0; it < 2; ++it) {
        int i = tid + it * 512;
        int r = i >> 4, c8 = (i & 15) << 3;
        *(bf16x8*)&As[buf][r * LD + c8] = rb[it];
      }
    }
  };

  int t = (int)blockIdx.x;
  int stride = (int)gridDim.x;
  if (t < ntiles) load_tile(t);

#pragma unroll
  for (int kc = 0; kc < 4; ++kc)
#pragma unroll
    for (int ni = 0; ni < NI; ++ni)
      asm volatile("" :: "v"(bq[kc][ni]));

  int buf = 0;
  while (t < ntiles) {
    write_tile(buf);
    __syncthreads();
    int tn = t + stride;
    if (tn < ntiles) load_tile(tn);  // prefetch under compute

    f32x4 acc[4][NI];
#pragma unroll
    for (int mi = 0; mi < 4; ++mi)
#pragma unroll
      for (int ni = 0; ni < NI; ++ni) acc[mi][ni] = (f32x4){0.f, 0.f, 0.f, 0.f};

#pragma unroll
    for (int kc = 0; kc < 4; ++kc) {
      int ko = kc * 32 + quad * 8;
      bf16x8 af[4];
#pragma unroll
      for (int mi = 0; mi < 4; ++mi)
        af[mi] = *(const bf16x8*)&As[buf][(mi * 16 + m) * LD + ko];
#pragma unroll
      for (int mi = 0; mi < 4; ++mi)
#pragma unroll
        for (int ni = 0; ni < NI; ++ni)
          acc[mi][ni] = __builtin_amdgcn_mfma_f32_16x16x32_bf16(af[mi], bq[kc][ni], acc[mi][ni], 0, 0, 0);
    }

    long row0 = (long)t * 64;
#pragma unroll
    for (int mi = 0; mi < 4; ++mi) {
#pragma unroll
      for (int r = 0; r < 4; ++r) {
        long grow = row0 + mi * 16 + quad * 4 + r;
        if (grow < nrows) {
#pragma unroll
          for (int ni = 0; ni < NI; ++ni) {
            long idx = grow * COLS + wcol + ni * 16 + m;
            float v = acc[mi][ni][r];
            if (panel == 0) outA[idx] = to_fp8(v);
            else            outB[idx] = (__bf16)v;
          }
        }
      }
    }
    t = tn;
    buf ^= 1;
  }
}

// ---------------- aggregation (proven R10 structure, full grids) ----------------

template <bool RELU>
__global__ __launch_bounds__(256) void k_agg128(const unsigned char* __restrict__ Y,
                                                const __bf16* __restrict__ XR,
                                                const float* __restrict__ bias,
                                                const int* __restrict__ rowptr,
                                                const int* __restrict__ col,
                                                __bf16* __restrict__ out, int nnodes) {
  int wave = threadIdx.x >> 6, lane = threadIdx.x & 63;
  int quarter = lane >> 4, l = lane & 15;
  int sb = lane & 48;
  int n = blockIdx.x * 16 + wave * 4 + quarter;
  bool valid = n < nnodes;
  int beg = 0, end = 0;
  if (valid) {
    beg = rowptr[n];
    end = rowptr[n + 1];
  }
  int co = l * 8;
  const unsigned char* Yc = Y + co;

  f32x2 av0 = {0.f, 0.f}, av1 = {0.f, 0.f}, av2 = {0.f, 0.f}, av3 = {0.f, 0.f};

  for (int base = beg; base < end; base += 16) {
    int cnt = min(end - base, 16);
    int idx = (l < cnt) ? col[base + l] : 0;
    int j = 0;
    for (; j + 3 < cnt; j += 4) {
      long s0 = (unsigned)__shfl(idx, sb + j);
      long s1 = (unsigned)__shfl(idx, sb + j + 1);
      long s2 = (unsigned)__shfl(idx, sb + j + 2);
      long s3 = (unsigned)__shfl(idx, sb + j + 3);
      uint2 v0 = *(const uint2*)(Yc + s0 * 128);
      uint2 v1 = *(const uint2*)(Yc + s1 * 128);
      uint2 v2 = *(const uint2*)(Yc + s2 * 128);
      uint2 v3 = *(const uint2*)(Yc + s3 * 128);
      av0 += fp8x2_lo(v0.x); av1 += fp8x2_hi(v0.x);
      av2 += fp8x2_lo(v0.y); av3 += fp8x2_hi(v0.y);
      av0 += fp8x2_lo(v1.x); av1 += fp8x2_hi(v1.x);
      av2 += fp8x2_lo(v1.y); av3 += fp8x2_hi(v1.y);
      av0 += fp8x2_lo(v2.x); av1 += fp8x2_hi(v2.x);
      av2 += fp8x2_lo(v2.y); av3 += fp8x2_hi(v2.y);
      av0 += fp8x2_lo(v3.x); av1 += fp8x2_hi(v3.x);
      av2 += fp8x2_lo(v3.y); av3 += fp8x2_hi(v3.y);
    }
    for (; j < cnt; ++j) {
      long s = (unsigned)__shfl(idx, sb + j);
      uint2 v = *(const uint2*)(Yc + s * 128);
      av0 += fp8x2_lo(v.x); av1 += fp8x2_hi(v.x);
      av2 += fp8x2_lo(v.y); av3 += fp8x2_hi(v.y);
    }
  }

  if (valid) {
    float inv = 1.f / (float)max(end - beg, 1);
    bf16x8 xv = *(const bf16x8*)(XR + (long)n * 128 + co);
    f32x4 b0 = *(const f32x4*)(bias + co);
    f32x4 b1 = *(const f32x4*)(bias + co + 4);
    float r0 = av0[0] * inv + (float)xv[0] + b0[0];
    float r1 = av0[1] * inv + (float)xv[1] + b0[1];
    float r2 = av1[0] * inv + (float)xv[2] + b0[2];
    float r3 = av1[1] * inv + (float)xv[3] + b0[3];
    float r4 = av2[0] * inv + (float)xv[4] + b1[0];
    float r5 = av2[1] * inv + (float)xv[5] + b1[1];
    float r6 = av3[0] * inv + (float)xv[6] + b1[2];
    float r7 = av3[1] * inv + (float)xv[7] + b1[3];
    if (RELU) {
      r0 = fmaxf(r0, 0.f); r1 = fmaxf(r1, 0.f);
      r2 = fmaxf(r2, 0.f); r3 = fmaxf(r3, 0.f);
      r4 = fmaxf(r4, 0.f); r5 = fmaxf(r5, 0.f);
      r6 = fmaxf(r6, 0.f); r7 = fmaxf(r7, 0.f);
    }
    bf16x8 o;
    o[0] = (__bf16)r0; o[1] = (__bf16)r1; o[2] = (__bf16)r2; o[3] = (__bf16)r3;
    o[4] = (__bf16)r4; o[5] = (__bf16)r5; o[6] = (__bf16)r6; o[7] = (__bf16)r7;
    *(bf16x8*)(out + (long)n * 128 + co) = o;
  }
}

__global__ __launch_bounds__(256) void k_agg64(const unsigned char* __restrict__ Y,
                                               const __bf16* __restrict__ XR,
                                               const float* __restrict__ bias,
                                               const int* __restrict__ rowptr,
                                               const int* __restrict__ col,
                                               float* __restrict__ out, int nnodes) {
  int wave = threadIdx.x >> 6, lane = threadIdx.x & 63;
  int quarter = lane >> 4, l = lane & 15;
  int sb = lane & 48;
  int n = blockIdx.x * 16 + wave * 4 + quarter;
  bool valid = n < nnodes;
  int beg = 0, end = 0;
  if (valid) {
    beg = rowptr[n];
    end = rowptr[n + 1];
  }
  int co = l * 4;
  const unsigned char* Yc = Y + co;

  f32x2 av0 = {0.f, 0.f}, av1 = {0.f, 0.f};

  for (int base = beg; base < end; base += 16) {
    int cnt = min(end - base, 16);
    int idx = (l < cnt) ? col[base + l] : 0;
    int j = 0;
    for (; j + 3 < cnt; j += 4) {
      long s0 = (unsigned)__shfl(idx, sb + j);
      long s1 = (unsigned)__shfl(idx, sb + j + 1);
      long s2 = (unsigned)__shfl(idx, sb + j + 2);
      long s3 = (unsigned)__shfl(idx, sb + j + 3);
      unsigned v0 = *(const unsigned*)(Yc + s0 * 64);
      unsigned v1 = *(const unsigned*)(Yc + s1 * 64);
      unsigned v2 = *(const unsigned*)(Yc + s2 * 64);
      unsigned v3 = *(const unsigned*)(Yc + s3 * 64);
      av0 += fp8x2_lo(v0); av1 += fp8x2_hi(v0);
      av0 += fp8x2_lo(v1); av1 += fp8x2_hi(v1);
      av0 += fp8x2_lo(v2); av1 += fp8x2_hi(v2);
      av0 += fp8x2_lo(v3); av1 += fp8x2_hi(v3);
    }
    for (; j < cnt; ++j) {
      long s = (unsigned)__shfl(idx, sb + j);
      unsigned v = *(const unsigned*)(Yc + s * 64);
      av0 += fp8x2_lo(v); av1 += fp8x2_hi(v);
    }
  }

  if (valid) {
    float inv = 1.f / (float)max(end - beg, 1);
    bf16x4 xv = *(const bf16x4*)(XR + (long)n * 64 + co);
    f32x4 bv = *(const f32x4*)(bias + co);
    f32x4 r;
    r[0] = av0[0] * inv + (float)xv[0] + bv[0];
    r[1] = av0[1] * inv + (float)xv[1] + bv[1];
    r[2] = av1[0] * inv + (float)xv[2] + bv[2];
    r[3] = av1[1] * inv + (float)xv[3] + bv[3];
    *(f32x4*)(out + (long)n * 64 + co) = r;
  }
}

// ---------------- launch ----------------

extern "C" void kernel_launch(void* const* d_in, const int* in_sizes, int n_in,
                              void* d_out, int out_size, void* d_ws, size_t ws_size,
                              hipStream_t stream) {
  const float* x   = (const float*)d_in[0];
  const int*   ei  = (const int*)d_in[1];
  const float* W1l = (const float*)d_in[2];
  const float* W1r = (const float*)d_in[3];
  const float* b1  = (const float*)d_in[4];
  const float* W2l = (const float*)d_in[5];
  const float* W2r = (const float*)d_in[6];
  const float* b2  = (const float*)d_in[7];
  float* out = (float*)d_out;

  int N = in_sizes[0] / K;   // 100000
  int E = in_sizes[1] / 2;   // 1600000
  const int* src = ei;
  const int* dst = ei + E;

  int nB = (N + 255) >> 8;          // 391 buckets of 256 nodes
  int nblk = (E + EB - 1) / EB;     // 391 scatter blocks

  char* ws = (char*)d_ws;
  size_t off = 0;
  auto alloc = [&](size_t bytes) {
    void* p = ws + off;
    off = (off + bytes + 255) & ~(size_t)255;
    return p;
  };
  int*      rowptr      = (int*)alloc(((size_t)N + 2) * 4);
  int*      col         = (int*)alloc((size_t)E * 4);
  int*      meta        = (int*)alloc(((size_t)nB + 80) * 4);  // bucketCount + tileCtr
  unsigned* recs        = (unsigned*)alloc((size_t)nB * CAP * 4);
  unsigned char* y1     = (unsigned char*)alloc((size_t)N * 128);  // fp8
  __bf16*   xr          = (__bf16*)alloc((size_t)N * 128 * 2);
  __bf16*   h           = (__bf16*)alloc((size_t)N * 128 * 2);
  unsigned char* y2 = y1;  // layer-1 gather buffer dead after agg128; reuse
  __bf16*   hr = xr;

  int* bucketCount = meta;
  int* tileCtr     = meta + nB + 16;  // 64B-separated from bucketCount

  int ntiles = (N + 63) / 64;
  int gpers = ntiles < 512 ? ntiles : 512;

  // fused: scatter (blocks 0..nblk-1, then join GEMM) ∥ GEMM1 (dynamic queue)
  hipMemsetAsync(meta, 0, ((size_t)nB + 80) * 4, stream);
  k_scatter_gemm<128><<<nblk + gpers, 512, 0, stream>>>(
      src, dst, bucketCount, recs, E, N, nB, nblk,
      tileCtr, x, W1l, W1r, y1, xr, ntiles);

  // rowptr/col fill (391 blocks; self-computed bucket prefix), then agg
  k_bfill<<<nB, 256, 0, stream>>>(recs, bucketCount, rowptr, col, N);
  k_agg128<true><<<(N + 15) / 16, 256, 0, stream>>>(y1, xr, b1, rowptr, col, h, N);

  // layer 2: y2 = fp8(h@W2l), hr = bf16(h@W2r)
  k_gemm_fused<64, __bf16><<<gpers, 512, 0, stream>>>(h, W2l, W2r, y2, hr, N, ntiles);

  // out = mean_gather(y2) + hr + b2
  k_agg64<<<(N + 15) / 16, 256, 0, stream>>>(y2, hr, b2, rowptr, col, out, N);
}